// Round 1
// baseline (4368.698 us; speedup 1.0000x reference)
//
#include <hip/hip_runtime.h>
#include <cmath>

#define N_   8
#define H_   56
#define W_   56
#define C_   256
#define HW_  3136
#define NHW_ 25088
#define G_   8
#define GC_  32
#define P_   9
#define HID_ 1024

// ---------------- block-wide sum of (a,b) over 256 threads ----------------
__device__ __forceinline__ float2 block_sum2(float a, float b, float* sm) {
    int lane = threadIdx.x & 63;
    int wid  = threadIdx.x >> 6;
#pragma unroll
    for (int off = 32; off > 0; off >>= 1) {
        a += __shfl_down(a, off, 64);
        b += __shfl_down(b, off, 64);
    }
    if (lane == 0) { sm[wid] = a; sm[wid + 4] = b; }
    __syncthreads();
    float ra = sm[0] + sm[1] + sm[2] + sm[3];
    float rb = sm[4] + sm[5] + sm[6] + sm[7];
    __syncthreads();
    return make_float2(ra, rb);
}

// ---------------- conv1 weight transpose: [co][ci][3][3] -> [kk][ci][co] ----------------
__global__ __launch_bounds__(256) void k_prep_wT(const float* __restrict__ w, float* __restrict__ wT) {
    int i  = blockIdx.x * 256 + threadIdx.x;      // 9*256*256 = 589824
    int co = i & 255;
    int r  = i >> 8;
    int ci = r & 255;
    int kk = r >> 8;                               // kh*3+kw
    wT[i] = w[(co * 256 + ci) * 9 + kk];
}

// ---------------- conv1 3x3 + BN1 + ReLU -> t (NHWC) ----------------
__global__ __launch_bounds__(256) void k_conv1(const float* __restrict__ x, const float* __restrict__ wT,
                                               const float* __restrict__ g, const float* __restrict__ b,
                                               const float* __restrict__ m, const float* __restrict__ v,
                                               float* __restrict__ t) {
    int pix = blockIdx.x;
    int n = pix / HW_, hw = pix - n * HW_;
    int h = hw / W_,  w = hw - h * W_;
    int co = threadIdx.x;
    const float* xb = x + (size_t)n * C_ * HW_;
    float acc = 0.f;
#pragma unroll
    for (int kh = 0; kh < 3; ++kh) {
        int y = h + kh - 1;
        if ((unsigned)y >= H_) continue;
#pragma unroll
        for (int kw = 0; kw < 3; ++kw) {
            int xx = w + kw - 1;
            if ((unsigned)xx >= W_) continue;
            const float* xp = xb + y * W_ + xx;                 // + ci*HW_
            const float* wp = wT + (kh * 3 + kw) * C_ * C_ + co; // + ci*C_ (coalesced)
#pragma unroll 8
            for (int ci = 0; ci < C_; ++ci)
                acc = fmaf(xp[ci * HW_], wp[ci * C_], acc);
        }
    }
    float s   = rsqrtf(v[co] + 1e-5f);
    float val = (acc - m[co]) * (g[co] * s) + b[co];
    t[(size_t)pix * C_ + co] = fmaxf(val, 0.f);
}

// ---------------- generic 256x256 GEMM + bias: out = in @ W + b ----------------
__global__ __launch_bounds__(256) void k_gemm256(const float* __restrict__ in, const float* __restrict__ W,
                                                 const float* __restrict__ bias, float* __restrict__ out) {
    __shared__ float sin_[8][256];
    int p0 = blockIdx.x * 8;
    int c  = threadIdx.x;
#pragma unroll
    for (int k = 0; k < 8; ++k) sin_[k][c] = in[(size_t)(p0 + k) * C_ + c];
    __syncthreads();
    float acc[8] = {};
#pragma unroll 4
    for (int k = 0; k < C_; ++k) {
        float wv = W[k * C_ + c];
#pragma unroll
        for (int px = 0; px < 8; ++px) acc[px] = fmaf(sin_[px][k], wv, acc[px]);
    }
    float bb = bias[c];
#pragma unroll
    for (int px = 0; px < 8; ++px) out[(size_t)(p0 + px) * C_ + c] = acc[px] + bb;
}

// ---------------- depthwise 3x3 + LN(1e-6) + exact GELU -> x1 ----------------
__global__ __launch_bounds__(256) void k_dw(const float* __restrict__ t, const float* __restrict__ dww,
                                            const float* __restrict__ dwb, const float* __restrict__ lg,
                                            const float* __restrict__ lb, float* __restrict__ x1) {
    __shared__ float sm[8];
    int pix = blockIdx.x;
    int n = pix / HW_, hw = pix - n * HW_;
    int h = hw / W_,  w = hw - h * W_;
    int c = threadIdx.x;
    float acc = dwb[c];
#pragma unroll
    for (int kh = 0; kh < 3; ++kh) {
        int y = h + kh - 1;
        if ((unsigned)y >= H_) continue;
#pragma unroll
        for (int kw = 0; kw < 3; ++kw) {
            int xx = w + kw - 1;
            if ((unsigned)xx >= W_) continue;
            acc = fmaf(t[(size_t)(n * HW_ + y * W_ + xx) * C_ + c], dww[(kh * 3 + kw) * C_ + c], acc);
        }
    }
    float2 r  = block_sum2(acc, acc * acc, sm);
    float mu  = r.x * (1.f / C_);
    float var = fmaxf(r.y * (1.f / C_) - mu * mu, 0.f);
    float rs  = rsqrtf(var + 1e-6f);
    float val = (acc - mu) * rs * lg[c] + lb[c];
    val = 0.5f * val * (1.f + erff(val * 0.70710678118654752f));
    x1[(size_t)pix * C_ + c] = val;
}

// ---------------- offset GEMM (256->144) + mask GEMM (256->72) + softmax ----------------
__global__ __launch_bounds__(256) void k_offmask(const float* __restrict__ x1,
                                                 const float* __restrict__ offw, const float* __restrict__ offb,
                                                 const float* __restrict__ mskw, const float* __restrict__ mskb,
                                                 float* __restrict__ offo, float* __restrict__ msko) {
    __shared__ float sin_[8][256];
    __shared__ float smk[8][72];
    int p0 = blockIdx.x * 8;
    int c  = threadIdx.x;
#pragma unroll
    for (int k = 0; k < 8; ++k) sin_[k][c] = x1[(size_t)(p0 + k) * C_ + c];
    __syncthreads();
    float acc[8] = {};
    if (c < 144) {
#pragma unroll 4
        for (int k = 0; k < C_; ++k) {
            float wv = offw[k * 144 + c];
#pragma unroll
            for (int px = 0; px < 8; ++px) acc[px] = fmaf(sin_[px][k], wv, acc[px]);
        }
        float bb = offb[c];
#pragma unroll
        for (int px = 0; px < 8; ++px) offo[(size_t)(p0 + px) * 144 + c] = acc[px] + bb;
    } else if (c < 216) {
        int cm = c - 144;
#pragma unroll 4
        for (int k = 0; k < C_; ++k) {
            float wv = mskw[k * 72 + cm];
#pragma unroll
            for (int px = 0; px < 8; ++px) acc[px] = fmaf(sin_[px][k], wv, acc[px]);
        }
        float bb = mskb[cm];
#pragma unroll
        for (int px = 0; px < 8; ++px) smk[px][cm] = acc[px] + bb;
    }
    __syncthreads();
    if (c < 64) {
        int px = c >> 3, g = c & 7;
        float mx = -1e30f;
#pragma unroll
        for (int p = 0; p < 9; ++p) mx = fmaxf(mx, smk[px][g * 9 + p]);
        float e[9], s = 0.f;
#pragma unroll
        for (int p = 0; p < 9; ++p) { e[p] = expf(smk[px][g * 9 + p] - mx); s += e[p]; }
        float inv = 1.f / s;
#pragma unroll
        for (int p = 0; p < 9; ++p) msko[(size_t)(p0 + px) * 72 + g * 9 + p] = e[p] * inv;
    }
}

// ---------------- DCNv3 deformable sampling core ----------------
__global__ __launch_bounds__(256) void k_core(const float* __restrict__ xp,
                                              const float* __restrict__ offo, const float* __restrict__ msko,
                                              float* __restrict__ core) {
    int pix = blockIdx.x;
    int n = pix / HW_, hw = pix - n * HW_;
    int h = hw / W_,  w = hw - h * W_;
    int g  = threadIdx.x >> 5;
    int cc = threadIdx.x & 31;
    const float* op = offo + (size_t)pix * 144 + g * 18;
    const float* mp = msko + (size_t)pix * 72 + g * 9;
    const float* xg = xp + (size_t)n * HW_ * C_ + g * GC_ + cc;
    float acc = 0.f;
#pragma unroll
    for (int p = 0; p < 9; ++p) {
        // padded-coord sample point: gx = w + i + off_x (i = p/3), gy = h + j + off_y (j = p%3)
        float gx = (float)(w + (p / 3)) + op[p * 2];
        float gy = (float)(h + (p % 3)) + op[p * 2 + 1];
        float fx = floorf(gx), fy = floorf(gy);
        float wx = gx - fx,   wy = gy - fy;
        int ix = (int)fx - 1, iy = (int)fy - 1;   // back to unpadded coords
        float v00 = 0.f, v10 = 0.f, v01 = 0.f, v11 = 0.f;
        bool x0ok = (unsigned)ix < W_, x1ok = (unsigned)(ix + 1) < W_;
        bool y0ok = (unsigned)iy < H_, y1ok = (unsigned)(iy + 1) < H_;
        if (y0ok) {
            const float* r = xg + (size_t)(iy * W_) * C_;
            if (x0ok) v00 = r[(size_t)ix * C_];
            if (x1ok) v10 = r[(size_t)(ix + 1) * C_];
        }
        if (y1ok) {
            const float* r = xg + (size_t)((iy + 1) * W_) * C_;
            if (x0ok) v01 = r[(size_t)ix * C_];
            if (x1ok) v11 = r[(size_t)(ix + 1) * C_];
        }
        float sval = (v00 * (1.f - wx) + v10 * wx) * (1.f - wy)
                   + (v01 * (1.f - wx) + v11 * wx) * wy;
        acc = fmaf(mp[p], sval, acc);
    }
    core[(size_t)pix * C_ + threadIdx.x] = acc;
}

// ---------------- output proj + LN(1e-5) + gamma1 residual into t ----------------
__global__ __launch_bounds__(256) void k_outproj(const float* __restrict__ core,
                                                 const float* __restrict__ Wo, const float* __restrict__ bo,
                                                 const float* __restrict__ g1, const float* __restrict__ lg,
                                                 const float* __restrict__ lb, float* __restrict__ t) {
    __shared__ float sin_[8][256];
    __shared__ float sm[8];
    int p0 = blockIdx.x * 8;
    int c  = threadIdx.x;
#pragma unroll
    for (int k = 0; k < 8; ++k) sin_[k][c] = core[(size_t)(p0 + k) * C_ + c];
    __syncthreads();
    float acc[8] = {};
#pragma unroll 4
    for (int k = 0; k < C_; ++k) {
        float wv = Wo[k * C_ + c];
#pragma unroll
        for (int px = 0; px < 8; ++px) acc[px] = fmaf(sin_[px][k], wv, acc[px]);
    }
    float bb = bo[c], gg = g1[c], lgc = lg[c], lbc = lb[c];
#pragma unroll
    for (int px = 0; px < 8; ++px) {
        float d   = acc[px] + bb;
        float2 r  = block_sum2(d, d * d, sm);
        float mu  = r.x * (1.f / C_);
        float var = fmaxf(r.y * (1.f / C_) - mu * mu, 0.f);
        float rs  = rsqrtf(var + 1e-5f);
        size_t idx = (size_t)(p0 + px) * C_ + c;
        t[idx] += gg * ((d - mu) * rs * lgc + lbc);
    }
}

// ---------------- fused MLP: gelu(t@fc1+b)@fc2+b, LN(1e-5), gamma2 residual ----------------
__global__ __launch_bounds__(256) void k_mlp(const float* __restrict__ fc1w, const float* __restrict__ fc1b,
                                             const float* __restrict__ fc2w, const float* __restrict__ fc2b,
                                             const float* __restrict__ g2, const float* __restrict__ lg,
                                             const float* __restrict__ lb, float* __restrict__ t) {
    __shared__ float st[8][256];
    __shared__ float sh[8][1024];
    __shared__ float sm[8];
    int p0 = blockIdx.x * 8;
    int c  = threadIdx.x;
#pragma unroll
    for (int k = 0; k < 8; ++k) st[k][c] = t[(size_t)(p0 + k) * C_ + c];
    __syncthreads();
#pragma unroll
    for (int q = 0; q < 4; ++q) {
        int cc = q * 256 + c;
        float acc[8] = {};
#pragma unroll 4
        for (int k = 0; k < C_; ++k) {
            float wv = fc1w[k * HID_ + cc];
#pragma unroll
            for (int px = 0; px < 8; ++px) acc[px] = fmaf(st[px][k], wv, acc[px]);
        }
        float bb = fc1b[cc];
#pragma unroll
        for (int px = 0; px < 8; ++px) {
            float vv = acc[px] + bb;
            sh[px][cc] = 0.5f * vv * (1.f + erff(vv * 0.70710678118654752f));
        }
    }
    __syncthreads();
    float acc2[8] = {};
#pragma unroll 4
    for (int k = 0; k < HID_; ++k) {
        float wv = fc2w[k * C_ + c];
#pragma unroll
        for (int px = 0; px < 8; ++px) acc2[px] = fmaf(sh[px][k], wv, acc2[px]);
    }
    float bb = fc2b[c], gg = g2[c], lgc = lg[c], lbc = lb[c];
#pragma unroll
    for (int px = 0; px < 8; ++px) {
        float hv  = acc2[px] + bb;
        float2 r  = block_sum2(hv, hv * hv, sm);
        float mu  = r.x * (1.f / C_);
        float var = fmaxf(r.y * (1.f / C_) - mu * mu, 0.f);
        float rs  = rsqrtf(var + 1e-5f);
        size_t idx = (size_t)(p0 + px) * C_ + c;
        t[idx] += gg * ((hv - mu) * rs * lgc + lbc);
    }
}

// ---------------- BN2 + input residual + ReLU -> out (NCHW) ----------------
__global__ __launch_bounds__(256) void k_final(const float* __restrict__ t, const float* __restrict__ x,
                                               const float* __restrict__ g, const float* __restrict__ b,
                                               const float* __restrict__ m, const float* __restrict__ v,
                                               float* __restrict__ out) {
    int i  = blockIdx.x * 256 + threadIdx.x;  // over N*C*HW = 6422528
    int hw = i % HW_;
    int r  = i / HW_;
    int c  = r & 255;
    int n  = r >> 8;
    float tv  = t[(size_t)(n * HW_ + hw) * C_ + c];
    float s   = rsqrtf(v[c] + 1e-5f);
    float val = (tv - m[c]) * (g[c] * s) + b[c] + x[i];
    out[i] = fmaxf(val, 0.f);
}

extern "C" void kernel_launch(void* const* d_in, const int* in_sizes, int n_in,
                              void* d_out, int out_size, void* d_ws, size_t ws_size,
                              hipStream_t stream) {
    const float* x      = (const float*)d_in[0];
    const float* conv1w = (const float*)d_in[1];
    const float* bn1g   = (const float*)d_in[2];
    const float* bn1b   = (const float*)d_in[3];
    const float* bn1m   = (const float*)d_in[4];
    const float* bn1v   = (const float*)d_in[5];
    const float* ln1g   = (const float*)d_in[6];
    const float* ln1b   = (const float*)d_in[7];
    const float* dww    = (const float*)d_in[8];
    const float* dwb    = (const float*)d_in[9];
    const float* dwlng  = (const float*)d_in[10];
    const float* dwlnb  = (const float*)d_in[11];
    const float* offw   = (const float*)d_in[12];
    const float* offb   = (const float*)d_in[13];
    const float* mskw   = (const float*)d_in[14];
    const float* mskb   = (const float*)d_in[15];
    const float* inpw   = (const float*)d_in[16];
    const float* inpb   = (const float*)d_in[17];
    const float* outpw  = (const float*)d_in[18];
    const float* outpb  = (const float*)d_in[19];
    const float* gamma1 = (const float*)d_in[20];
    const float* ln2g   = (const float*)d_in[21];
    const float* ln2b   = (const float*)d_in[22];
    const float* fc1w   = (const float*)d_in[23];
    const float* fc1b   = (const float*)d_in[24];
    const float* fc2w   = (const float*)d_in[25];
    const float* fc2b   = (const float*)d_in[26];
    const float* gamma2 = (const float*)d_in[27];
    const float* bn2g   = (const float*)d_in[28];
    const float* bn2b   = (const float*)d_in[29];
    const float* bn2m   = (const float*)d_in[30];
    const float* bn2v   = (const float*)d_in[31];
    float* out = (float*)d_out;

    float* ws    = (float*)d_ws;
    float* t     = ws;                                  // [NHW][256]
    float* xproj = t     + (size_t)NHW_ * C_;           // [NHW][256]
    float* x1b   = xproj + (size_t)NHW_ * C_;           // [NHW][256]
    float* offo  = x1b   + (size_t)NHW_ * C_;           // [NHW][144]
    float* msko  = offo  + (size_t)NHW_ * 144;          // [NHW][72]
    float* coreb = msko  + (size_t)NHW_ * 72;           // [NHW][256]
    float* wT    = coreb + (size_t)NHW_ * C_;           // [9][256][256]

    k_prep_wT<<<2304, 256, 0, stream>>>(conv1w, wT);
    k_conv1  <<<NHW_, 256, 0, stream>>>(x, wT, bn1g, bn1b, bn1m, bn1v, t);
    k_gemm256<<<NHW_ / 8, 256, 0, stream>>>(t, inpw, inpb, xproj);
    k_dw     <<<NHW_, 256, 0, stream>>>(t, dww, dwb, dwlng, dwlnb, x1b);
    k_offmask<<<NHW_ / 8, 256, 0, stream>>>(x1b, offw, offb, mskw, mskb, offo, msko);
    k_core   <<<NHW_, 256, 0, stream>>>(xproj, offo, msko, coreb);
    k_outproj<<<NHW_ / 8, 256, 0, stream>>>(coreb, outpw, outpb, gamma1, ln1g, ln1b, t);
    k_mlp    <<<NHW_ / 8, 256, 0, stream>>>(fc1w, fc1b, fc2w, fc2b, gamma2, ln2g, ln2b, t);
    k_final  <<<NHW_, 256, 0, stream>>>(t, x, bn2g, bn2b, bn2m, bn2v, out);
}

// Round 2
// 1428.302 us; speedup vs baseline: 3.0587x; 3.0587x over previous
//
#include <hip/hip_runtime.h>
#include <cmath>

#define N_   8
#define H_   56
#define W_   56
#define C_   256
#define HW_  3136
#define NHW_ 25088
#define G_   8
#define GC_  32
#define P_   9
#define HID_ 1024
#define XP_H 58
#define XP_W 58

typedef __attribute__((ext_vector_type(8))) short bf16x8;
typedef __attribute__((ext_vector_type(4))) float f32x4;

__device__ __forceinline__ unsigned short f2bf(float f) {
    unsigned u = __float_as_uint(f);
    u += 0x7FFF + ((u >> 16) & 1);   // round-to-nearest-even
    return (unsigned short)(u >> 16);
}

// ---------------- block-wide sum of (a,b) over 256 threads ----------------
__device__ __forceinline__ float2 block_sum2(float a, float b, float* sm) {
    int lane = threadIdx.x & 63;
    int wid  = threadIdx.x >> 6;
#pragma unroll
    for (int off = 32; off > 0; off >>= 1) {
        a += __shfl_down(a, off, 64);
        b += __shfl_down(b, off, 64);
    }
    if (lane == 0) { sm[wid] = a; sm[wid + 4] = b; }
    __syncthreads();
    float ra = sm[0] + sm[1] + sm[2] + sm[3];
    float rb = sm[4] + sm[5] + sm[6] + sm[7];
    __syncthreads();
    return make_float2(ra, rb);
}

// ---------------- x (NCHW fp32) -> xpad (N,58,58,256 bf16), border pre-zeroed ----------------
__global__ __launch_bounds__(256) void k_prep_xpad(const float* __restrict__ x, unsigned short* __restrict__ xpad) {
    int nh = blockIdx.x;                   // N_*H_ = 448
    int n = nh / H_, h = nh - n * H_;
    int c = threadIdx.x;
    const float* xr = x + ((size_t)(n * C_ + c)) * HW_ + h * W_;
    unsigned short* orow = xpad + ((size_t)((n * XP_H + h + 1) * XP_W + 1)) * C_ + c;
    for (int w = 0; w < W_; ++w) orow[(size_t)w * C_] = f2bf(xr[w]);
}

// ---------------- conv1 weights [co][ci][3][3] -> wTT [kk][co][ci] bf16 ----------------
__global__ __launch_bounds__(256) void k_prep_wTT(const float* __restrict__ w, unsigned short* __restrict__ wTT) {
    int i  = blockIdx.x * 256 + threadIdx.x;   // 9*256*256 = 589824
    int ci = i & 255;
    int r  = i >> 8;
    int co = r & 255;
    int kk = r >> 8;
    wTT[i] = f2bf(w[(co * 256 + ci) * 9 + kk]);
}

// ---------------- conv1 via MFMA implicit GEMM + BN1 + ReLU -> t (NHWC fp32) ----------------
// block = 256 thr (4 waves); each block: 32 pixels x 256 co; wave w: co quadrant w*64.
__global__ __launch_bounds__(256) void k_conv1_mfma(const unsigned short* __restrict__ xpad,
                                                    const unsigned short* __restrict__ wTT,
                                                    const float* __restrict__ g, const float* __restrict__ b,
                                                    const float* __restrict__ m, const float* __restrict__ v,
                                                    float* __restrict__ t) {
    int wave = threadIdx.x >> 6;
    int lane = threadIdx.x & 63;
    int r    = lane & 15;          // A-row / B-col / D-col within fragment
    int kq   = lane >> 4;          // k-quadrant: k = kq*8 + j
    int co0  = wave * 64;
    int p0   = blockIdx.x * 32;

    size_t abase[2];
#pragma unroll
    for (int mi = 0; mi < 2; ++mi) {
        int pix = p0 + mi * 16 + r;
        int n = pix / HW_, hw = pix - n * HW_;
        int h = hw / W_,  w = hw - h * W_;
        abase[mi] = ((size_t)((n * XP_H + h) * XP_W + w)) * C_ + kq * 8;
    }

    f32x4 acc[2][4] = {};
#pragma unroll 1
    for (int tap = 0; tap < 9; ++tap) {
        int kh = tap / 3, kw = tap - kh * 3;
        size_t aoff = (size_t)(kh * XP_W + kw) * C_;
        const unsigned short* bp = wTT + ((size_t)(tap * C_) + co0 + r) * C_ + kq * 8;
        const unsigned short* a0p = xpad + abase[0] + aoff;
        const unsigned short* a1p = xpad + abase[1] + aoff;
#pragma unroll
        for (int ks = 0; ks < 8; ++ks) {
            bf16x8 a0 = *(const bf16x8*)(a0p + ks * 32);
            bf16x8 a1 = *(const bf16x8*)(a1p + ks * 32);
            bf16x8 b0 = *(const bf16x8*)(bp + 0 * 16 * C_ + ks * 32);
            bf16x8 b1 = *(const bf16x8*)(bp + 1 * 16 * C_ + ks * 32);
            bf16x8 b2 = *(const bf16x8*)(bp + 2 * 16 * C_ + ks * 32);
            bf16x8 b3 = *(const bf16x8*)(bp + 3 * 16 * C_ + ks * 32);
            acc[0][0] = __builtin_amdgcn_mfma_f32_16x16x32_bf16(a0, b0, acc[0][0], 0, 0, 0);
            acc[0][1] = __builtin_amdgcn_mfma_f32_16x16x32_bf16(a0, b1, acc[0][1], 0, 0, 0);
            acc[0][2] = __builtin_amdgcn_mfma_f32_16x16x32_bf16(a0, b2, acc[0][2], 0, 0, 0);
            acc[0][3] = __builtin_amdgcn_mfma_f32_16x16x32_bf16(a0, b3, acc[0][3], 0, 0, 0);
            acc[1][0] = __builtin_amdgcn_mfma_f32_16x16x32_bf16(a1, b0, acc[1][0], 0, 0, 0);
            acc[1][1] = __builtin_amdgcn_mfma_f32_16x16x32_bf16(a1, b1, acc[1][1], 0, 0, 0);
            acc[1][2] = __builtin_amdgcn_mfma_f32_16x16x32_bf16(a1, b2, acc[1][2], 0, 0, 0);
            acc[1][3] = __builtin_amdgcn_mfma_f32_16x16x32_bf16(a1, b3, acc[1][3], 0, 0, 0);
        }
    }

#pragma unroll
    for (int ni = 0; ni < 4; ++ni) {
        int co = co0 + ni * 16 + r;
        float sc = g[co] * rsqrtf(v[co] + 1e-5f);
        float sh = b[co] - m[co] * sc;
#pragma unroll
        for (int mi = 0; mi < 2; ++mi) {
#pragma unroll
            for (int reg = 0; reg < 4; ++reg) {
                int pix = p0 + mi * 16 + kq * 4 + reg;
                float val = acc[mi][ni][reg] * sc + sh;
                t[(size_t)pix * C_ + co] = fmaxf(val, 0.f);
            }
        }
    }
}

// ---------------- generic 256x256 GEMM + bias: out = in @ W + b ----------------
__global__ __launch_bounds__(256) void k_gemm256(const float* __restrict__ in, const float* __restrict__ W,
                                                 const float* __restrict__ bias, float* __restrict__ out) {
    __shared__ float sin_[8][256];
    int p0 = blockIdx.x * 8;
    int c  = threadIdx.x;
#pragma unroll
    for (int k = 0; k < 8; ++k) sin_[k][c] = in[(size_t)(p0 + k) * C_ + c];
    __syncthreads();
    float acc[8] = {};
#pragma unroll 4
    for (int k = 0; k < C_; ++k) {
        float wv = W[k * C_ + c];
#pragma unroll
        for (int px = 0; px < 8; ++px) acc[px] = fmaf(sin_[px][k], wv, acc[px]);
    }
    float bb = bias[c];
#pragma unroll
    for (int px = 0; px < 8; ++px) out[(size_t)(p0 + px) * C_ + c] = acc[px] + bb;
}

// ---------------- depthwise 3x3 + LN(1e-6) + exact GELU -> x1 ----------------
__global__ __launch_bounds__(256) void k_dw(const float* __restrict__ t, const float* __restrict__ dww,
                                            const float* __restrict__ dwb, const float* __restrict__ lg,
                                            const float* __restrict__ lb, float* __restrict__ x1) {
    __shared__ float sm[8];
    int pix = blockIdx.x;
    int n = pix / HW_, hw = pix - n * HW_;
    int h = hw / W_,  w = hw - h * W_;
    int c = threadIdx.x;
    float acc = dwb[c];
#pragma unroll
    for (int kh = 0; kh < 3; ++kh) {
        int y = h + kh - 1;
        if ((unsigned)y >= H_) continue;
#pragma unroll
        for (int kw = 0; kw < 3; ++kw) {
            int xx = w + kw - 1;
            if ((unsigned)xx >= W_) continue;
            acc = fmaf(t[(size_t)(n * HW_ + y * W_ + xx) * C_ + c], dww[(kh * 3 + kw) * C_ + c], acc);
        }
    }
    float2 r  = block_sum2(acc, acc * acc, sm);
    float mu  = r.x * (1.f / C_);
    float var = fmaxf(r.y * (1.f / C_) - mu * mu, 0.f);
    float rs  = rsqrtf(var + 1e-6f);
    float val = (acc - mu) * rs * lg[c] + lb[c];
    val = 0.5f * val * (1.f + erff(val * 0.70710678118654752f));
    x1[(size_t)pix * C_ + c] = val;
}

// ---------------- offset GEMM (256->144) + mask GEMM (256->72) + softmax ----------------
__global__ __launch_bounds__(256) void k_offmask(const float* __restrict__ x1,
                                                 const float* __restrict__ offw, const float* __restrict__ offb,
                                                 const float* __restrict__ mskw, const float* __restrict__ mskb,
                                                 float* __restrict__ offo, float* __restrict__ msko) {
    __shared__ float sin_[8][256];
    __shared__ float smk[8][72];
    int p0 = blockIdx.x * 8;
    int c  = threadIdx.x;
#pragma unroll
    for (int k = 0; k < 8; ++k) sin_[k][c] = x1[(size_t)(p0 + k) * C_ + c];
    __syncthreads();
    float acc[8] = {};
    if (c < 144) {
#pragma unroll 4
        for (int k = 0; k < C_; ++k) {
            float wv = offw[k * 144 + c];
#pragma unroll
            for (int px = 0; px < 8; ++px) acc[px] = fmaf(sin_[px][k], wv, acc[px]);
        }
        float bb = offb[c];
#pragma unroll
        for (int px = 0; px < 8; ++px) offo[(size_t)(p0 + px) * 144 + c] = acc[px] + bb;
    } else if (c < 216) {
        int cm = c - 144;
#pragma unroll 4
        for (int k = 0; k < C_; ++k) {
            float wv = mskw[k * 72 + cm];
#pragma unroll
            for (int px = 0; px < 8; ++px) acc[px] = fmaf(sin_[px][k], wv, acc[px]);
        }
        float bb = mskb[cm];
#pragma unroll
        for (int px = 0; px < 8; ++px) smk[px][cm] = acc[px] + bb;
    }
    __syncthreads();
    if (c < 64) {
        int px = c >> 3, g = c & 7;
        float mx = -1e30f;
#pragma unroll
        for (int p = 0; p < 9; ++p) mx = fmaxf(mx, smk[px][g * 9 + p]);
        float e[9], s = 0.f;
#pragma unroll
        for (int p = 0; p < 9; ++p) { e[p] = expf(smk[px][g * 9 + p] - mx); s += e[p]; }
        float inv = 1.f / s;
#pragma unroll
        for (int p = 0; p < 9; ++p) msko[(size_t)(p0 + px) * 72 + g * 9 + p] = e[p] * inv;
    }
}

// ---------------- DCNv3 deformable sampling core ----------------
__global__ __launch_bounds__(256) void k_core(const float* __restrict__ xp,
                                              const float* __restrict__ offo, const float* __restrict__ msko,
                                              float* __restrict__ core) {
    int pix = blockIdx.x;
    int n = pix / HW_, hw = pix - n * HW_;
    int h = hw / W_,  w = hw - h * W_;
    int g  = threadIdx.x >> 5;
    int cc = threadIdx.x & 31;
    const float* op = offo + (size_t)pix * 144 + g * 18;
    const float* mp = msko + (size_t)pix * 72 + g * 9;
    const float* xg = xp + (size_t)n * HW_ * C_ + g * GC_ + cc;
    float acc = 0.f;
#pragma unroll
    for (int p = 0; p < 9; ++p) {
        float gx = (float)(w + (p / 3)) + op[p * 2];
        float gy = (float)(h + (p % 3)) + op[p * 2 + 1];
        float fx = floorf(gx), fy = floorf(gy);
        float wx = gx - fx,   wy = gy - fy;
        int ix = (int)fx - 1, iy = (int)fy - 1;
        float v00 = 0.f, v10 = 0.f, v01 = 0.f, v11 = 0.f;
        bool x0ok = (unsigned)ix < W_, x1ok = (unsigned)(ix + 1) < W_;
        bool y0ok = (unsigned)iy < H_, y1ok = (unsigned)(iy + 1) < H_;
        if (y0ok) {
            const float* rr = xg + (size_t)(iy * W_) * C_;
            if (x0ok) v00 = rr[(size_t)ix * C_];
            if (x1ok) v10 = rr[(size_t)(ix + 1) * C_];
        }
        if (y1ok) {
            const float* rr = xg + (size_t)((iy + 1) * W_) * C_;
            if (x0ok) v01 = rr[(size_t)ix * C_];
            if (x1ok) v11 = rr[(size_t)(ix + 1) * C_];
        }
        float sval = (v00 * (1.f - wx) + v10 * wx) * (1.f - wy)
                   + (v01 * (1.f - wx) + v11 * wx) * wy;
        acc = fmaf(mp[p], sval, acc);
    }
    core[(size_t)pix * C_ + threadIdx.x] = acc;
}

// ---------------- output proj + LN(1e-5) + gamma1 residual into t ----------------
__global__ __launch_bounds__(256) void k_outproj(const float* __restrict__ core,
                                                 const float* __restrict__ Wo, const float* __restrict__ bo,
                                                 const float* __restrict__ g1, const float* __restrict__ lg,
                                                 const float* __restrict__ lb, float* __restrict__ t) {
    __shared__ float sin_[8][256];
    __shared__ float sm[8];
    int p0 = blockIdx.x * 8;
    int c  = threadIdx.x;
#pragma unroll
    for (int k = 0; k < 8; ++k) sin_[k][c] = core[(size_t)(p0 + k) * C_ + c];
    __syncthreads();
    float acc[8] = {};
#pragma unroll 4
    for (int k = 0; k < C_; ++k) {
        float wv = Wo[k * C_ + c];
#pragma unroll
        for (int px = 0; px < 8; ++px) acc[px] = fmaf(sin_[px][k], wv, acc[px]);
    }
    float bb = bo[c], gg = g1[c], lgc = lg[c], lbc = lb[c];
#pragma unroll
    for (int px = 0; px < 8; ++px) {
        float d   = acc[px] + bb;
        float2 r  = block_sum2(d, d * d, sm);
        float mu  = r.x * (1.f / C_);
        float var = fmaxf(r.y * (1.f / C_) - mu * mu, 0.f);
        float rs  = rsqrtf(var + 1e-5f);
        size_t idx = (size_t)(p0 + px) * C_ + c;
        t[idx] += gg * ((d - mu) * rs * lgc + lbc);
    }
}

// ---------------- fused MLP: gelu(t@fc1+b)@fc2+b, LN(1e-5), gamma2 residual ----------------
__global__ __launch_bounds__(256) void k_mlp(const float* __restrict__ fc1w, const float* __restrict__ fc1b,
                                             const float* __restrict__ fc2w, const float* __restrict__ fc2b,
                                             const float* __restrict__ g2, const float* __restrict__ lg,
                                             const float* __restrict__ lb, float* __restrict__ t) {
    __shared__ float st[8][256];
    __shared__ float sh[8][1024];
    __shared__ float sm[8];
    int p0 = blockIdx.x * 8;
    int c  = threadIdx.x;
#pragma unroll
    for (int k = 0; k < 8; ++k) st[k][c] = t[(size_t)(p0 + k) * C_ + c];
    __syncthreads();
#pragma unroll
    for (int q = 0; q < 4; ++q) {
        int cc = q * 256 + c;
        float acc[8] = {};
#pragma unroll 4
        for (int k = 0; k < C_; ++k) {
            float wv = fc1w[k * HID_ + cc];
#pragma unroll
            for (int px = 0; px < 8; ++px) acc[px] = fmaf(st[px][k], wv, acc[px]);
        }
        float bb = fc1b[cc];
#pragma unroll
        for (int px = 0; px < 8; ++px) {
            float vv = acc[px] + bb;
            sh[px][cc] = 0.5f * vv * (1.f + erff(vv * 0.70710678118654752f));
        }
    }
    __syncthreads();
    float acc2[8] = {};
#pragma unroll 4
    for (int k = 0; k < HID_; ++k) {
        float wv = fc2w[k * C_ + c];
#pragma unroll
        for (int px = 0; px < 8; ++px) acc2[px] = fmaf(sh[px][k], wv, acc2[px]);
    }
    float bb = fc2b[c], gg = g2[c], lgc = lg[c], lbc = lb[c];
#pragma unroll
    for (int px = 0; px < 8; ++px) {
        float hv  = acc2[px] + bb;
        float2 r  = block_sum2(hv, hv * hv, sm);
        float mu  = r.x * (1.f / C_);
        float var = fmaxf(r.y * (1.f / C_) - mu * mu, 0.f);
        float rs  = rsqrtf(var + 1e-5f);
        size_t idx = (size_t)(p0 + px) * C_ + c;
        t[idx] += gg * ((hv - mu) * rs * lgc + lbc);
    }
}

// ---------------- BN2 + input residual + ReLU -> out (NCHW) ----------------
__global__ __launch_bounds__(256) void k_final(const float* __restrict__ t, const float* __restrict__ x,
                                               const float* __restrict__ g, const float* __restrict__ b,
                                               const float* __restrict__ m, const float* __restrict__ v,
                                               float* __restrict__ out) {
    int i  = blockIdx.x * 256 + threadIdx.x;
    int hw = i % HW_;
    int r  = i / HW_;
    int c  = r & 255;
    int n  = r >> 8;
    float tv  = t[(size_t)(n * HW_ + hw) * C_ + c];
    float s   = rsqrtf(v[c] + 1e-5f);
    float val = (tv - m[c]) * (g[c] * s) + b[c] + x[i];
    out[i] = fmaxf(val, 0.f);
}

extern "C" void kernel_launch(void* const* d_in, const int* in_sizes, int n_in,
                              void* d_out, int out_size, void* d_ws, size_t ws_size,
                              hipStream_t stream) {
    const float* x      = (const float*)d_in[0];
    const float* conv1w = (const float*)d_in[1];
    const float* bn1g   = (const float*)d_in[2];
    const float* bn1b   = (const float*)d_in[3];
    const float* bn1m   = (const float*)d_in[4];
    const float* bn1v   = (const float*)d_in[5];
    const float* ln1g   = (const float*)d_in[6];
    const float* ln1b   = (const float*)d_in[7];
    const float* dww    = (const float*)d_in[8];
    const float* dwb    = (const float*)d_in[9];
    const float* dwlng  = (const float*)d_in[10];
    const float* dwlnb  = (const float*)d_in[11];
    const float* offw   = (const float*)d_in[12];
    const float* offb   = (const float*)d_in[13];
    const float* mskw   = (const float*)d_in[14];
    const float* mskb   = (const float*)d_in[15];
    const float* inpw   = (const float*)d_in[16];
    const float* inpb   = (const float*)d_in[17];
    const float* outpw  = (const float*)d_in[18];
    const float* outpb  = (const float*)d_in[19];
    const float* gamma1 = (const float*)d_in[20];
    const float* ln2g   = (const float*)d_in[21];
    const float* ln2b   = (const float*)d_in[22];
    const float* fc1w   = (const float*)d_in[23];
    const float* fc1b   = (const float*)d_in[24];
    const float* fc2w   = (const float*)d_in[25];
    const float* fc2b   = (const float*)d_in[26];
    const float* gamma2 = (const float*)d_in[27];
    const float* bn2g   = (const float*)d_in[28];
    const float* bn2b   = (const float*)d_in[29];
    const float* bn2m   = (const float*)d_in[30];
    const float* bn2v   = (const float*)d_in[31];
    float* out = (float*)d_out;

    float* ws    = (float*)d_ws;
    float* t     = ws;                                  // [NHW][256] f32
    float* xproj = t     + (size_t)NHW_ * C_;           // [NHW][256] f32
    float* x1b   = xproj + (size_t)NHW_ * C_;           // [NHW][256] f32
    float* offo  = x1b   + (size_t)NHW_ * C_;           // [NHW][144] f32
    float* msko  = offo  + (size_t)NHW_ * 144;          // [NHW][72]  f32
    float* coreb = msko  + (size_t)NHW_ * 72;           // [NHW][256] f32
    // conv1 scratch aliases coreb (coreb is first written by k_core, after conv1 is done):
    unsigned short* xpad = (unsigned short*)coreb;                         // [8][58][58][256] bf16 = 13.78 MB
    unsigned short* wTT  = xpad + (size_t)N_ * XP_H * XP_W * C_;           // [9][256][256] bf16 = 1.18 MB

    hipMemsetAsync(xpad, 0, (size_t)N_ * XP_H * XP_W * C_ * sizeof(unsigned short), stream);
    k_prep_xpad<<<N_ * H_, 256, 0, stream>>>(x, xpad);
    k_prep_wTT <<<2304,    256, 0, stream>>>(conv1w, wTT);
    k_conv1_mfma<<<NHW_ / 32, 256, 0, stream>>>(xpad, wTT, bn1g, bn1b, bn1m, bn1v, t);

    k_gemm256<<<NHW_ / 8, 256, 0, stream>>>(t, inpw, inpb, xproj);
    k_dw     <<<NHW_, 256, 0, stream>>>(t, dww, dwb, dwlng, dwlnb, x1b);
    k_offmask<<<NHW_ / 8, 256, 0, stream>>>(x1b, offw, offb, mskw, mskb, offo, msko);
    k_core   <<<NHW_, 256, 0, stream>>>(xproj, offo, msko, coreb);
    k_outproj<<<NHW_ / 8, 256, 0, stream>>>(coreb, outpw, outpb, gamma1, ln1g, ln1b, t);
    k_mlp    <<<NHW_ / 8, 256, 0, stream>>>(fc1w, fc1b, fc2w, fc2b, gamma2, ln2g, ln2b, t);
    k_final  <<<NHW_, 256, 0, stream>>>(t, x, bn2g, bn2b, bn2m, bn2v, out);
}

// Round 4
// 866.992 us; speedup vs baseline: 5.0389x; 1.6474x over previous
//
#include <hip/hip_runtime.h>
#include <cmath>

#define N_   8
#define H_   56
#define W_   56
#define C_   256
#define HW_  3136
#define NHW_ 25088
#define G_   8
#define GC_  32
#define P_   9
#define HID_ 1024
#define XP_H 58
#define XP_W 58

typedef __attribute__((ext_vector_type(8))) short bf16x8;
typedef __attribute__((ext_vector_type(4))) float f32x4;

__device__ __forceinline__ unsigned short f2bf(float f) {
    unsigned u = __float_as_uint(f);
    u += 0x7FFF + ((u >> 16) & 1);   // round-to-nearest-even
    return (unsigned short)(u >> 16);
}

__device__ __forceinline__ float gelu_exact(float v) {
    return 0.5f * v * (1.f + erff(v * 0.70710678118654752f));
}

// ---------------- block-wide sum of (a,b) over 256 threads ----------------
__device__ __forceinline__ float2 block_sum2(float a, float b, float* sm) {
    int lane = threadIdx.x & 63;
    int wid  = threadIdx.x >> 6;
#pragma unroll
    for (int off = 32; off > 0; off >>= 1) {
        a += __shfl_down(a, off, 64);
        b += __shfl_down(b, off, 64);
    }
    if (lane == 0) { sm[wid] = a; sm[wid + 4] = b; }
    __syncthreads();
    float ra = sm[0] + sm[1] + sm[2] + sm[3];
    float rb = sm[4] + sm[5] + sm[6] + sm[7];
    __syncthreads();
    return make_float2(ra, rb);
}

// ---------------- x (NCHW fp32) -> xpad (N,58,58,256 bf16), border pre-zeroed ----------------
__global__ __launch_bounds__(256) void k_prep_xpad(const float* __restrict__ x, unsigned short* __restrict__ xpad) {
    int nh = blockIdx.x;                   // N_*H_ = 448
    int n = nh / H_, h = nh - n * H_;
    int c = threadIdx.x;
    const float* xr = x + ((size_t)(n * C_ + c)) * HW_ + h * W_;
    unsigned short* orow = xpad + ((size_t)((n * XP_H + h + 1) * XP_W + 1)) * C_ + c;
    for (int w = 0; w < W_; ++w) orow[(size_t)w * C_] = f2bf(xr[w]);
}

// ---------------- conv1 weights [co][ci][3][3] -> wTT [kk][co][ci] bf16 ----------------
__global__ __launch_bounds__(256) void k_prep_wTT(const float* __restrict__ w, unsigned short* __restrict__ wTT) {
    int i  = blockIdx.x * 256 + threadIdx.x;   // 9*256*256
    int ci = i & 255;
    int r  = i >> 8;
    int co = r & 255;
    int kk = r >> 8;
    wTT[i] = f2bf(w[(co * 256 + ci) * 9 + kk]);
}

// ---------------- square 256x256 weight -> W^T bf16 [n][k] ----------------
__global__ __launch_bounds__(256) void k_prep_sqT(const float* __restrict__ src, unsigned short* __restrict__ dst) {
    int n = blockIdx.x, k = threadIdx.x;
    dst[n * C_ + k] = f2bf(src[k * C_ + n]);
}

// ---------------- fc1 [256][1024] -> [1024][256] bf16 ----------------
__global__ __launch_bounds__(256) void k_prep_fc1T(const float* __restrict__ src, unsigned short* __restrict__ dst) {
    int n = blockIdx.x, k = threadIdx.x;
    dst[(size_t)n * C_ + k] = f2bf(src[(size_t)k * HID_ + n]);
}

// ---------------- fc2 [1024][256] -> [256][1024] bf16 ----------------
__global__ __launch_bounds__(256) void k_prep_fc2T(const float* __restrict__ src, unsigned short* __restrict__ dst) {
    int n = blockIdx.x, k0 = threadIdx.x;
#pragma unroll
    for (int q = 0; q < 4; ++q) {
        int k = q * 256 + k0;
        dst[(size_t)n * HID_ + k] = f2bf(src[(size_t)k * C_ + n]);
    }
}

// ---------------- offw[256][144] + mskw[256][72] -> omT [256][256] bf16 (+ omb) ----------------
__global__ __launch_bounds__(256) void k_prep_om(const float* __restrict__ offw, const float* __restrict__ offb,
                                                 const float* __restrict__ mskw, const float* __restrict__ mskb,
                                                 unsigned short* __restrict__ omT, float* __restrict__ omb) {
    int n = blockIdx.x, k = threadIdx.x;
    float v = 0.f;
    if (n < 144)      v = offw[k * 144 + n];
    else if (n < 216) v = mskw[k * 72 + (n - 144)];
    omT[n * C_ + k] = f2bf(v);
    if (k == 0) omb[n] = (n < 144) ? offb[n] : (n < 216 ? mskb[n - 144] : 0.f);
}

// ---------------- conv1 via MFMA implicit GEMM + BN1 + ReLU -> t (f32) + t_bf ----------------
__global__ __launch_bounds__(256) void k_conv1_mfma(const unsigned short* __restrict__ xpad,
                                                    const unsigned short* __restrict__ wTT,
                                                    const float* __restrict__ g, const float* __restrict__ b,
                                                    const float* __restrict__ m, const float* __restrict__ v,
                                                    float* __restrict__ t, unsigned short* __restrict__ t_bf) {
    int wave = threadIdx.x >> 6;
    int lane = threadIdx.x & 63;
    int r    = lane & 15;
    int kq   = lane >> 4;
    int co0  = wave * 64;
    int p0   = blockIdx.x * 32;

    size_t abase[2];
#pragma unroll
    for (int mi = 0; mi < 2; ++mi) {
        int pix = p0 + mi * 16 + r;
        int n = pix / HW_, hw = pix - n * HW_;
        int h = hw / W_,  w = hw - h * W_;
        abase[mi] = ((size_t)((n * XP_H + h) * XP_W + w)) * C_ + kq * 8;
    }

    f32x4 acc[2][4] = {};
#pragma unroll 1
    for (int tap = 0; tap < 9; ++tap) {
        int kh = tap / 3, kw = tap - kh * 3;
        size_t aoff = (size_t)(kh * XP_W + kw) * C_;
        const unsigned short* bp = wTT + ((size_t)(tap * C_) + co0 + r) * C_ + kq * 8;
        const unsigned short* a0p = xpad + abase[0] + aoff;
        const unsigned short* a1p = xpad + abase[1] + aoff;
#pragma unroll
        for (int ks = 0; ks < 8; ++ks) {
            bf16x8 a0 = *(const bf16x8*)(a0p + ks * 32);
            bf16x8 a1 = *(const bf16x8*)(a1p + ks * 32);
            bf16x8 b0 = *(const bf16x8*)(bp + 0 * 16 * C_ + ks * 32);
            bf16x8 b1 = *(const bf16x8*)(bp + 1 * 16 * C_ + ks * 32);
            bf16x8 b2 = *(const bf16x8*)(bp + 2 * 16 * C_ + ks * 32);
            bf16x8 b3 = *(const bf16x8*)(bp + 3 * 16 * C_ + ks * 32);
            acc[0][0] = __builtin_amdgcn_mfma_f32_16x16x32_bf16(a0, b0, acc[0][0], 0, 0, 0);
            acc[0][1] = __builtin_amdgcn_mfma_f32_16x16x32_bf16(a0, b1, acc[0][1], 0, 0, 0);
            acc[0][2] = __builtin_amdgcn_mfma_f32_16x16x32_bf16(a0, b2, acc[0][2], 0, 0, 0);
            acc[0][3] = __builtin_amdgcn_mfma_f32_16x16x32_bf16(a0, b3, acc[0][3], 0, 0, 0);
            acc[1][0] = __builtin_amdgcn_mfma_f32_16x16x32_bf16(a1, b0, acc[1][0], 0, 0, 0);
            acc[1][1] = __builtin_amdgcn_mfma_f32_16x16x32_bf16(a1, b1, acc[1][1], 0, 0, 0);
            acc[1][2] = __builtin_amdgcn_mfma_f32_16x16x32_bf16(a1, b2, acc[1][2], 0, 0, 0);
            acc[1][3] = __builtin_amdgcn_mfma_f32_16x16x32_bf16(a1, b3, acc[1][3], 0, 0, 0);
        }
    }

#pragma unroll
    for (int ni = 0; ni < 4; ++ni) {
        int co = co0 + ni * 16 + r;
        float sc = g[co] * rsqrtf(v[co] + 1e-5f);
        float sh = b[co] - m[co] * sc;
#pragma unroll
        for (int mi = 0; mi < 2; ++mi) {
#pragma unroll
            for (int reg = 0; reg < 4; ++reg) {
                int pix = p0 + mi * 16 + kq * 4 + reg;
                float val = fmaxf(acc[mi][ni][reg] * sc + sh, 0.f);
                size_t idx = (size_t)pix * C_ + co;
                t[idx] = val;
                t_bf[idx] = f2bf(val);
            }
        }
    }
}

// ---------------- input proj via MFMA: xproj = t_bf @ inpwT^T + b (f32 out) ----------------
__global__ __launch_bounds__(256) void k_inproj_mfma(const unsigned short* __restrict__ t_bf,
                                                     const unsigned short* __restrict__ inpwT,
                                                     const float* __restrict__ bias,
                                                     float* __restrict__ xproj) {
    int wave = threadIdx.x >> 6, lane = threadIdx.x & 63;
    int r = lane & 15, kq = lane >> 4;
    int p0 = blockIdx.x * 32, co0 = wave * 64;
    f32x4 acc[2][4] = {};
#pragma unroll 1
    for (int ks = 0; ks < 8; ++ks) {
        bf16x8 a0 = *(const bf16x8*)(t_bf + (size_t)(p0 + r) * C_ + ks * 32 + kq * 8);
        bf16x8 a1 = *(const bf16x8*)(t_bf + (size_t)(p0 + 16 + r) * C_ + ks * 32 + kq * 8);
        const unsigned short* bp = inpwT + (size_t)(co0 + r) * C_ + ks * 32 + kq * 8;
#pragma unroll
        for (int ni = 0; ni < 4; ++ni) {
            bf16x8 b = *(const bf16x8*)(bp + (size_t)ni * 16 * C_);
            acc[0][ni] = __builtin_amdgcn_mfma_f32_16x16x32_bf16(a0, b, acc[0][ni], 0, 0, 0);
            acc[1][ni] = __builtin_amdgcn_mfma_f32_16x16x32_bf16(a1, b, acc[1][ni], 0, 0, 0);
        }
    }
#pragma unroll
    for (int ni = 0; ni < 4; ++ni) {
        int col = co0 + ni * 16 + r;
        float bb = bias[col];
#pragma unroll
        for (int mi = 0; mi < 2; ++mi)
#pragma unroll
            for (int reg = 0; reg < 4; ++reg) {
                int pix = p0 + mi * 16 + kq * 4 + reg;
                xproj[(size_t)pix * C_ + col] = acc[mi][ni][reg] + bb;
            }
    }
}

// ---------------- depthwise 3x3 + LN(1e-6) + exact GELU -> x1_bf ----------------
__global__ __launch_bounds__(256) void k_dw(const float* __restrict__ t, const float* __restrict__ dww,
                                            const float* __restrict__ dwb, const float* __restrict__ lg,
                                            const float* __restrict__ lb, unsigned short* __restrict__ x1_bf) {
    __shared__ float sm[8];
    int pix = blockIdx.x;
    int n = pix / HW_, hw = pix - n * HW_;
    int h = hw / W_,  w = hw - h * W_;
    int c = threadIdx.x;
    float acc = dwb[c];
#pragma unroll
    for (int kh = 0; kh < 3; ++kh) {
        int y = h + kh - 1;
        if ((unsigned)y >= H_) continue;
#pragma unroll
        for (int kw = 0; kw < 3; ++kw) {
            int xx = w + kw - 1;
            if ((unsigned)xx >= W_) continue;
            acc = fmaf(t[(size_t)(n * HW_ + y * W_ + xx) * C_ + c], dww[(kh * 3 + kw) * C_ + c], acc);
        }
    }
    float2 r  = block_sum2(acc, acc * acc, sm);
    float mu  = r.x * (1.f / C_);
    float var = fmaxf(r.y * (1.f / C_) - mu * mu, 0.f);
    float rs  = rsqrtf(var + 1e-6f);
    float val = (acc - mu) * rs * lg[c] + lb[c];
    x1_bf[(size_t)pix * C_ + c] = f2bf(gelu_exact(val));
}

// ---------------- offset+mask via MFMA (N=256: 144 off | 72 msk | 40 pad) + softmax ----------------
__global__ __launch_bounds__(256) void k_offmask_mfma(const unsigned short* __restrict__ x1_bf,
                                                      const unsigned short* __restrict__ omT,
                                                      const float* __restrict__ omb,
                                                      float* __restrict__ offo, float* __restrict__ msko) {
    __shared__ float som[32][225];
    int wave = threadIdx.x >> 6, lane = threadIdx.x & 63;
    int r = lane & 15, kq = lane >> 4;
    int p0 = blockIdx.x * 32, co0 = wave * 64;
    f32x4 acc[2][4] = {};
#pragma unroll 1
    for (int ks = 0; ks < 8; ++ks) {
        bf16x8 a0 = *(const bf16x8*)(x1_bf + (size_t)(p0 + r) * C_ + ks * 32 + kq * 8);
        bf16x8 a1 = *(const bf16x8*)(x1_bf + (size_t)(p0 + 16 + r) * C_ + ks * 32 + kq * 8);
        const unsigned short* bp = omT + (size_t)(co0 + r) * C_ + ks * 32 + kq * 8;
#pragma unroll
        for (int ni = 0; ni < 4; ++ni) {
            bf16x8 b = *(const bf16x8*)(bp + (size_t)ni * 16 * C_);
            acc[0][ni] = __builtin_amdgcn_mfma_f32_16x16x32_bf16(a0, b, acc[0][ni], 0, 0, 0);
            acc[1][ni] = __builtin_amdgcn_mfma_f32_16x16x32_bf16(a1, b, acc[1][ni], 0, 0, 0);
        }
    }
#pragma unroll
    for (int ni = 0; ni < 4; ++ni) {
        int col = co0 + ni * 16 + r;
        if (col < 216) {
            float bb = omb[col];
#pragma unroll
            for (int mi = 0; mi < 2; ++mi)
#pragma unroll
                for (int reg = 0; reg < 4; ++reg)
                    som[mi * 16 + kq * 4 + reg][col] = acc[mi][ni][reg] + bb;
        }
    }
    __syncthreads();
    int tid = threadIdx.x;
#pragma unroll
    for (int i = 0; i < 18; ++i) {
        int j = i * 256 + tid;          // 32*144 = 4608
        int px = j / 144, col = j - px * 144;
        offo[(size_t)(p0 + px) * 144 + col] = som[px][col];
    }
    int px = tid >> 3, g = tid & 7;
    float mx = -1e30f;
#pragma unroll
    for (int p = 0; p < 9; ++p) mx = fmaxf(mx, som[px][144 + g * 9 + p]);
    float e[9], s = 0.f;
#pragma unroll
    for (int p = 0; p < 9; ++p) { e[p] = expf(som[px][144 + g * 9 + p] - mx); s += e[p]; }
    float inv = 1.f / s;
#pragma unroll
    for (int p = 0; p < 9; ++p) msko[(size_t)(p0 + px) * 72 + g * 9 + p] = e[p] * inv;
}

// ---------------- DCNv3 deformable sampling core -> core_bf ----------------
__global__ __launch_bounds__(256) void k_core(const float* __restrict__ xp,
                                              const float* __restrict__ offo, const float* __restrict__ msko,
                                              unsigned short* __restrict__ core_bf) {
    int pix = blockIdx.x;
    int n = pix / HW_, hw = pix - n * HW_;
    int h = hw / W_,  w = hw - h * W_;
    int g  = threadIdx.x >> 5;
    int cc = threadIdx.x & 31;
    const float* op = offo + (size_t)pix * 144 + g * 18;
    const float* mp = msko + (size_t)pix * 72 + g * 9;
    const float* xg = xp + (size_t)n * HW_ * C_ + g * GC_ + cc;
    float acc = 0.f;
#pragma unroll
    for (int p = 0; p < 9; ++p) {
        float gx = (float)(w + (p / 3)) + op[p * 2];
        float gy = (float)(h + (p % 3)) + op[p * 2 + 1];
        float fx = floorf(gx), fy = floorf(gy);
        float wx = gx - fx,   wy = gy - fy;
        int ix = (int)fx - 1, iy = (int)fy - 1;
        float v00 = 0.f, v10 = 0.f, v01 = 0.f, v11 = 0.f;
        bool x0ok = (unsigned)ix < W_, x1ok = (unsigned)(ix + 1) < W_;
        bool y0ok = (unsigned)iy < H_, y1ok = (unsigned)(iy + 1) < H_;
        if (y0ok) {
            const float* rr = xg + (size_t)(iy * W_) * C_;
            if (x0ok) v00 = rr[(size_t)ix * C_];
            if (x1ok) v10 = rr[(size_t)(ix + 1) * C_];
        }
        if (y1ok) {
            const float* rr = xg + (size_t)((iy + 1) * W_) * C_;
            if (x0ok) v01 = rr[(size_t)ix * C_];
            if (x1ok) v11 = rr[(size_t)(ix + 1) * C_];
        }
        float sval = (v00 * (1.f - wx) + v10 * wx) * (1.f - wy)
                   + (v01 * (1.f - wx) + v11 * wx) * wy;
        acc = fmaf(mp[p], sval, acc);
    }
    core_bf[(size_t)pix * C_ + threadIdx.x] = f2bf(acc);
}

// ---------------- output proj MFMA + LN(1e-5) + gamma1 residual -> t, t_bf ----------------
__global__ __launch_bounds__(256) void k_outproj_mfma(const unsigned short* __restrict__ core_bf,
                                                      const unsigned short* __restrict__ outpwT,
                                                      const float* __restrict__ bo,
                                                      const float* __restrict__ g1, const float* __restrict__ lg,
                                                      const float* __restrict__ lb,
                                                      float* __restrict__ t, unsigned short* __restrict__ t_bf) {
    __shared__ float sd[32][260];
    int wave = threadIdx.x >> 6, lane = threadIdx.x & 63;
    int r = lane & 15, kq = lane >> 4;
    int p0 = blockIdx.x * 32, co0 = wave * 64;
    f32x4 acc[2][4] = {};
#pragma unroll 1
    for (int ks = 0; ks < 8; ++ks) {
        bf16x8 a0 = *(const bf16x8*)(core_bf + (size_t)(p0 + r) * C_ + ks * 32 + kq * 8);
        bf16x8 a1 = *(const bf16x8*)(core_bf + (size_t)(p0 + 16 + r) * C_ + ks * 32 + kq * 8);
        const unsigned short* bp = outpwT + (size_t)(co0 + r) * C_ + ks * 32 + kq * 8;
#pragma unroll
        for (int ni = 0; ni < 4; ++ni) {
            bf16x8 b = *(const bf16x8*)(bp + (size_t)ni * 16 * C_);
            acc[0][ni] = __builtin_amdgcn_mfma_f32_16x16x32_bf16(a0, b, acc[0][ni], 0, 0, 0);
            acc[1][ni] = __builtin_amdgcn_mfma_f32_16x16x32_bf16(a1, b, acc[1][ni], 0, 0, 0);
        }
    }
#pragma unroll
    for (int ni = 0; ni < 4; ++ni) {
        int col = co0 + ni * 16 + r;
        float bb = bo[col];
#pragma unroll
        for (int mi = 0; mi < 2; ++mi)
#pragma unroll
            for (int reg = 0; reg < 4; ++reg)
                sd[mi * 16 + kq * 4 + reg][col] = acc[mi][ni][reg] + bb;
    }
    __syncthreads();
    int px = threadIdx.x >> 3, sub = threadIdx.x & 7;
    float s1 = 0.f, s2 = 0.f;
#pragma unroll
    for (int i = 0; i < 8; ++i) {
        float4 vv = *(const float4*)&sd[px][sub * 32 + i * 4];
        s1 += vv.x + vv.y + vv.z + vv.w;
        s2 += vv.x * vv.x + vv.y * vv.y + vv.z * vv.z + vv.w * vv.w;
    }
#pragma unroll
    for (int off = 1; off < 8; off <<= 1) { s1 += __shfl_xor(s1, off, 64); s2 += __shfl_xor(s2, off, 64); }
    float mu  = s1 * (1.f / C_);
    float var = fmaxf(s2 * (1.f / C_) - mu * mu, 0.f);
    float rs  = rsqrtf(var + 1e-5f);
#pragma unroll
    for (int i = 0; i < 32; ++i) {
        int col = sub * 32 + i;
        size_t idx = (size_t)(p0 + px) * C_ + col;
        float tn = t[idx] + g1[col] * ((sd[px][col] - mu) * rs * lg[col] + lb[col]);
        t[idx] = tn;
        t_bf[idx] = f2bf(tn);
    }
}

// ---------------- fused MLP via MFMA + LN + gamma2 residual into t ----------------
__global__ __launch_bounds__(256) void k_mlp_mfma(const unsigned short* __restrict__ t_bf,
                                                  const unsigned short* __restrict__ fc1wT, const float* __restrict__ fc1b,
                                                  const unsigned short* __restrict__ fc2wT, const float* __restrict__ fc2b,
                                                  const float* __restrict__ g2, const float* __restrict__ lg,
                                                  const float* __restrict__ lb, float* __restrict__ t) {
    __shared__ unsigned short sh[16][1032];
    __shared__ float ot[16][260];
    int wave = threadIdx.x >> 6, lane = threadIdx.x & 63;
    int r = lane & 15, kq = lane >> 4;
    int p0 = blockIdx.x * 16;
    int hc0 = wave * 256;

    // fc1: 16px x 1024hid, wave owns 256 hid cols
    f32x4 acc1[16] = {};
    const unsigned short* ap = t_bf + (size_t)(p0 + r) * C_ + kq * 8;
#pragma unroll 1
    for (int ks = 0; ks < 8; ++ks) {
        bf16x8 a = *(const bf16x8*)(ap + ks * 32);
        const unsigned short* bp = fc1wT + (size_t)(hc0 + r) * C_ + ks * 32 + kq * 8;
#pragma unroll
        for (int ni = 0; ni < 16; ++ni) {
            bf16x8 b = *(const bf16x8*)(bp + (size_t)(ni * 16) * C_);
            acc1[ni] = __builtin_amdgcn_mfma_f32_16x16x32_bf16(a, b, acc1[ni], 0, 0, 0);
        }
    }
#pragma unroll
    for (int ni = 0; ni < 16; ++ni) {
        int col = hc0 + ni * 16 + r;
        float bb = fc1b[col];
#pragma unroll
        for (int reg = 0; reg < 4; ++reg)
            sh[kq * 4 + reg][col] = f2bf(gelu_exact(acc1[ni][reg] + bb));
    }
    __syncthreads();

    // fc2: K=1024 from LDS, wave owns 64 out cols
    f32x4 acc2[4] = {};
    int co0 = wave * 64;
#pragma unroll 1
    for (int ks = 0; ks < 32; ++ks) {
        bf16x8 a = *(const bf16x8*)(&sh[r][ks * 32 + kq * 8]);
        const unsigned short* bp = fc2wT + (size_t)(co0 + r) * HID_ + ks * 32 + kq * 8;
#pragma unroll
        for (int ni = 0; ni < 4; ++ni) {
            bf16x8 b = *(const bf16x8*)(bp + (size_t)(ni * 16) * HID_);
            acc2[ni] = __builtin_amdgcn_mfma_f32_16x16x32_bf16(a, b, acc2[ni], 0, 0, 0);
        }
    }
#pragma unroll
    for (int ni = 0; ni < 4; ++ni) {
        int col = co0 + ni * 16 + r;
        float bb = fc2b[col];
#pragma unroll
        for (int reg = 0; reg < 4; ++reg)
            ot[kq * 4 + reg][col] = acc2[ni][reg] + bb;
    }
    __syncthreads();

    // LN + residual: 16 threads per pixel
    int px = threadIdx.x >> 4, sub = threadIdx.x & 15;
    float s1 = 0.f, s2 = 0.f;
#pragma unroll
    for (int i = 0; i < 4; ++i) {
        float4 vv = *(const float4*)&ot[px][sub * 16 + i * 4];
        s1 += vv.x + vv.y + vv.z + vv.w;
        s2 += vv.x * vv.x + vv.y * vv.y + vv.z * vv.z + vv.w * vv.w;
    }
#pragma unroll
    for (int off = 1; off < 16; off <<= 1) { s1 += __shfl_xor(s1, off, 64); s2 += __shfl_xor(s2, off, 64); }
    float mu  = s1 * (1.f / C_);
    float var = fmaxf(s2 * (1.f / C_) - mu * mu, 0.f);
    float rs  = rsqrtf(var + 1e-5f);
#pragma unroll
    for (int i = 0; i < 16; ++i) {
        int col = sub * 16 + i;
        size_t idx = (size_t)(p0 + px) * C_ + col;
        float hv = ot[px][col];
        t[idx] += g2[col] * ((hv - mu) * rs * lg[col] + lb[col]);
    }
}

// ---------------- BN2 + input residual + ReLU -> out (NCHW) ----------------
__global__ __launch_bounds__(256) void k_final(const float* __restrict__ t, const float* __restrict__ x,
                                               const float* __restrict__ g, const float* __restrict__ b,
                                               const float* __restrict__ m, const float* __restrict__ v,
                                               float* __restrict__ out) {
    int i  = blockIdx.x * 256 + threadIdx.x;
    int hw = i % HW_;
    int r  = i / HW_;
    int c  = r & 255;
    int n  = r >> 8;
    float tv  = t[(size_t)(n * HW_ + hw) * C_ + c];
    float s   = rsqrtf(v[c] + 1e-5f);
    float val = (tv - m[c]) * (g[c] * s) + b[c] + x[i];
    out[i] = fmaxf(val, 0.f);
}

extern "C" void kernel_launch(void* const* d_in, const int* in_sizes, int n_in,
                              void* d_out, int out_size, void* d_ws, size_t ws_size,
                              hipStream_t stream) {
    const float* x      = (const float*)d_in[0];
    const float* conv1w = (const float*)d_in[1];
    const float* bn1g   = (const float*)d_in[2];
    const float* bn1b   = (const float*)d_in[3];
    const float* bn1m   = (const float*)d_in[4];
    const float* bn1v   = (const float*)d_in[5];
    const float* ln1g   = (const float*)d_in[6];
    const float* ln1b   = (const float*)d_in[7];
    const float* dww    = (const float*)d_in[8];
    const float* dwb    = (const float*)d_in[9];
    const float* dwlng  = (const float*)d_in[10];
    const float* dwlnb  = (const float*)d_in[11];
    const float* offw   = (const float*)d_in[12];
    const float* offb   = (const float*)d_in[13];
    const float* mskw   = (const float*)d_in[14];
    const float* mskb   = (const float*)d_in[15];
    const float* inpw   = (const float*)d_in[16];
    const float* inpb   = (const float*)d_in[17];
    const float* outpw  = (const float*)d_in[18];
    const float* outpb  = (const float*)d_in[19];
    const float* gamma1 = (const float*)d_in[20];
    const float* ln2g   = (const float*)d_in[21];
    const float* ln2b   = (const float*)d_in[22];
    const float* fc1w   = (const float*)d_in[23];
    const float* fc1b   = (const float*)d_in[24];
    const float* fc2w   = (const float*)d_in[25];
    const float* fc2b   = (const float*)d_in[26];
    const float* gamma2 = (const float*)d_in[27];
    const float* bn2g   = (const float*)d_in[28];
    const float* bn2b   = (const float*)d_in[29];
    const float* bn2m   = (const float*)d_in[30];
    const float* bn2v   = (const float*)d_in[31];
    float* out = (float*)d_out;

    // ---- workspace layout ----
    float* ws    = (float*)d_ws;
    float* t     = ws;                                   // [NHW][256] f32
    float* xproj = t     + (size_t)NHW_ * C_;            // [NHW][256] f32
    float* offo  = xproj + (size_t)NHW_ * C_;            // [NHW][144] f32
    float* msko  = offo  + (size_t)NHW_ * 144;           // [NHW][72]  f32
    float* omb   = msko  + (size_t)NHW_ * 72;            // [256] f32
    unsigned short* t_bf  = (unsigned short*)(omb + 256);          // [NHW][256]
    unsigned short* x1_bf = t_bf  + (size_t)NHW_ * C_;             // [NHW][256]
    unsigned short* scr   = x1_bf + (size_t)NHW_ * C_;             // xpad [8*58*58*256] / core_bf alias
    unsigned short* wTT   = scr   + (size_t)N_ * XP_H * XP_W * C_; // [9][256][256]
    unsigned short* inpwT = wTT   + (size_t)9 * C_ * C_;           // [256][256]
    unsigned short* outpwT= inpwT + (size_t)C_ * C_;
    unsigned short* fc1wT = outpwT+ (size_t)C_ * C_;               // [1024][256]
    unsigned short* fc2wT = fc1wT + (size_t)HID_ * C_;             // [256][1024]
    unsigned short* omT   = fc2wT + (size_t)C_ * HID_;             // [256][256]
    unsigned short* xpad    = scr;
    unsigned short* core_bf = scr;

    hipMemsetAsync(xpad, 0, (size_t)N_ * XP_H * XP_W * C_ * sizeof(unsigned short), stream);
    k_prep_xpad<<<N_ * H_, 256, 0, stream>>>(x, xpad);
    k_prep_wTT <<<2304,    256, 0, stream>>>(conv1w, wTT);
    k_prep_sqT <<<256,     256, 0, stream>>>(inpw, inpwT);
    k_prep_sqT <<<256,     256, 0, stream>>>(outpw, outpwT);
    k_prep_fc1T<<<1024,    256, 0, stream>>>(fc1w, fc1wT);
    k_prep_fc2T<<<256,     256, 0, stream>>>(fc2w, fc2wT);
    k_prep_om  <<<256,     256, 0, stream>>>(offw, offb, mskw, mskb, omT, omb);

    k_conv1_mfma  <<<NHW_ / 32, 256, 0, stream>>>(xpad, wTT, bn1g, bn1b, bn1m, bn1v, t, t_bf);
    k_inproj_mfma <<<NHW_ / 32, 256, 0, stream>>>(t_bf, inpwT, inpb, xproj);
    k_dw          <<<NHW_,      256, 0, stream>>>(t, dww, dwb, dwlng, dwlnb, x1_bf);
    k_offmask_mfma<<<NHW_ / 32, 256, 0, stream>>>(x1_bf, omT, omb, offo, msko);
    k_core        <<<NHW_,      256, 0, stream>>>(xproj, offo, msko, core_bf);
    k_outproj_mfma<<<NHW_ / 32, 256, 0, stream>>>(core_bf, outpwT, outpb, gamma1, ln1g, ln1b, t, t_bf);
    k_mlp_mfma    <<<NHW_ / 16, 256, 0, stream>>>(t_bf, fc1wT, fc1b, fc2wT, fc2b, gamma2, ln2g, ln2b, t);
    k_final       <<<NHW_,      256, 0, stream>>>(t, x, bn2g, bn2b, bn2m, bn2v, out);
}